// Round 6
// baseline (665.892 us; speedup 1.0000x reference)
//
#include <hip/hip_runtime.h>

// LSTM: B=2048, T=2048, I=1, H=16, O=26.
//
// Round-6: R4/R5's lean 1-batch layout failed twice with bit-identical
// wrong output despite runtime-certified lane primitives — abandoned
// (un-debuggable from source). This round returns to the CERTIFIED Round-3
// dataflow (passed, absmax 9.7e-4) with ONE change: the two bit4 halves of
// each wave compute the SAME batch (b independent of g), so B=2048 batches
// occupy 2048 waves = 2 waves/SIMD. Tests the TLP hypothesis (R1-R3 show
// ~4+ cyc wall per instruction at 1 wave/SIMD = unfilled latency bubbles)
// with near-zero correctness risk: per-batch math is bit-identical to R3,
// and all cross-lane ops (partner32 = bit5 flip, DPP row_ror) stay within
// the duplicated halves.
//
// Layout: lane = j(0..15) | bit4 = duplicate copy | bit5 = gate pair
// (0:{i,g~}, 1:{f,o}). One batch per wave.

static constexpr int T_DIM = 2048;
static constexpr int H_DIM = 16;
static constexpr int O_DIM = 26;

typedef __attribute__((ext_vector_type(2))) float f32x2;

#define EXP2F(v) __builtin_amdgcn_exp2f(v)
#define RCPF(v)  __builtin_amdgcn_rcpf(v)

// DPP row rotate within 16-lane rows; 0x120|r = row_ror:r (r>=1).
#define ROR_I(x, r) __builtin_amdgcn_update_dpp((x), (x), 0x120 + (r), 0xF, 0xF, false)
#define ROR_F(x, r) __builtin_bit_cast(float, ROR_I(__builtin_bit_cast(int, (x)), (r)))

#if __has_builtin(__builtin_amdgcn_permlane32_swap)
#define HAS_PSWAP 1
#else
#define HAS_PSWAP 0
#endif

// bit5 exchange — identical binary behavior to R3 (passed), keep as-is.
__device__ __forceinline__ float partner32(float xf, bool psel_lo) {
#if HAS_PSWAP
    int xi = __builtin_bit_cast(int, xf);
    auto pr = __builtin_amdgcn_permlane32_swap(xi, xi, false, false);
    int lo, hi;
    __builtin_memcpy(&lo, &pr, 4);
    __builtin_memcpy(&hi, reinterpret_cast<const char*>(&pr) + 4, 4);
    return __builtin_bit_cast(float, psel_lo ? lo : hi);
#else
    (void)psel_lo;
    return __shfl_xor(xf, 32, 64);
#endif
}

// Packed dual-FP32 ops (VOP3P, full rate — confirmed by R3 delta).
__device__ __forceinline__ f32x2 pk_fma(f32x2 a, f32x2 b, f32x2 c) {
    f32x2 d;
    asm("v_pk_fma_f32 %0, %1, %2, %3" : "=v"(d) : "v"(a), "v"(b), "v"(c));
    return d;
}

__global__ __launch_bounds__(256, 2) void lstm_fused(
    const float* __restrict__ x,      // [B, T]
    const float* __restrict__ w_ih,   // [64]
    const float* __restrict__ w_hh,   // [64, 16]
    const float* __restrict__ b_ih,   // [64]
    const float* __restrict__ b_hh,   // [64]
    const float* __restrict__ w_out,  // [26, 16]
    const float* __restrict__ b_out,  // [26]
    float* __restrict__ out)          // [B, 26]
{
    const int tid   = threadIdx.x;
    const int wv    = tid >> 6;            // wave in block: 0..3
    const int lane  = tid & 63;
    const int j     = lane & 15;
    const bool halfb = (lane >= 32);       // gate pair (0:{i,g~}, 1:{f,o})
    const int b     = (blockIdx.x << 2) + wv;   // ONE batch per wave (dup halves)

    const int row0 = (halfb ? 16 : 0) + j;        // i or f
    const int row1 = 32 + (halfb ? 16 : 0) + j;   // g~ or o

    // --- DPP direction probes (init-only): idx[r] = source j delivered here.
    int idx[16];
    idx[0]  = j;
    idx[1]  = ROR_I(j, 1);   idx[2]  = ROR_I(j, 2);
    idx[3]  = ROR_I(j, 3);   idx[4]  = ROR_I(j, 4);
    idx[5]  = ROR_I(j, 5);   idx[6]  = ROR_I(j, 6);
    idx[7]  = ROR_I(j, 7);   idx[8]  = ROR_I(j, 8);
    idx[9]  = ROR_I(j, 9);   idx[10] = ROR_I(j, 10);
    idx[11] = ROR_I(j, 11);  idx[12] = ROR_I(j, 12);
    idx[13] = ROR_I(j, 13);  idx[14] = ROR_I(j, 14);
    idx[15] = ROR_I(j, 15);

    // --- permlane32_swap output-order probe (per-lane, semantics-proof).
    bool psel_lo = false;
#if HAS_PSWAP
    {
        auto pr = __builtin_amdgcn_permlane32_swap(lane, lane, false, false);
        int lo, hi;
        __builtin_memcpy(&lo, &pr, 4);
        __builtin_memcpy(&hi, reinterpret_cast<const char*>(&pr) + 4, 4);
        psel_lo = (lo == (lane ^ 32));
    }
#endif

    // --- activation scale constants, folded into weights/biases ---
    const float L2E = 1.44269504088896340736f;
    const float SC  = -2.0f * L2E;               // g~-row / cell scale
    const float sc0 = -L2E;                      // i,f,o rows
    const float sc1 = halfb ? sc0 : SC;          // row1: o (half1) / g~ (half0)

    // Pre-permuted, pre-scaled recurrent weights as (k, k+8) pk pairs.
    f32x2 wp0[8], wp1[8];
    #pragma unroll
    for (int r = 0; r < 8; ++r) {
        wp0[r] = (f32x2){w_hh[row0 * H_DIM + idx[r]] * sc0,
                         w_hh[row0 * H_DIM + idx[r + 8]] * sc0};
        wp1[r] = (f32x2){w_hh[row1 * H_DIM + idx[r]] * sc1,
                         w_hh[row1 * H_DIM + idx[r + 8]] * sc1};
    }
    const float wih0  = w_ih[row0] * sc0;
    const float wih1  = w_ih[row1] * sc1;
    const float bias0 = (b_ih[row0] + b_hh[row0]) * sc0;
    const float bias1 = (b_ih[row1] + b_hh[row1]) * sc1;

    // a1 post-fma constants: half0 -> SC*tanh(g) = 2SC*sig - SC ; half1 -> sig.
    const float k2 = halfb ? 1.0f : 2.0f * SC;
    const float k3 = halfb ? 0.0f : -SC;

    float C = 0.0f;   // scaled cell state: C = SC * c
    float h = 0.0f;

    const float4* xp = reinterpret_cast<const float4*>(x + (size_t)b * T_DIM);
    float4 xq = xp[0];

    for (int t4 = 0; t4 < T_DIM / 4; ++t4) {
        float4 xnext = xp[(t4 + 1) & (T_DIM / 4 - 1)];  // wraps harmlessly
        const float xa[4] = {xq.x, xq.y, xq.z, xq.w};

        #pragma unroll
        for (int s = 0; s < 4; ++s) {
            // --- 16 alignments of h as 8 pk pairs (15 independent DPPs) ---
            f32x2 rp[8];
            rp[0][0] = h;            rp[0][1] = ROR_F(h, 8);
            rp[1][0] = ROR_F(h, 1);  rp[1][1] = ROR_F(h, 9);
            rp[2][0] = ROR_F(h, 2);  rp[2][1] = ROR_F(h, 10);
            rp[3][0] = ROR_F(h, 3);  rp[3][1] = ROR_F(h, 11);
            rp[4][0] = ROR_F(h, 4);  rp[4][1] = ROR_F(h, 12);
            rp[5][0] = ROR_F(h, 5);  rp[5][1] = ROR_F(h, 13);
            rp[6][0] = ROR_F(h, 6);  rp[6][1] = ROR_F(h, 14);
            rp[7][0] = ROR_F(h, 7);  rp[7][1] = ROR_F(h, 15);

            // --- gate matvec: 8 pk_fma per row, x+bias rides in init C ---
            f32x2 p0 = pk_fma(rp[0], wp0[0], (f32x2){fmaf(xa[s], wih0, bias0), 0.0f});
            f32x2 p1 = pk_fma(rp[0], wp1[0], (f32x2){fmaf(xa[s], wih1, bias1), 0.0f});
            #pragma unroll
            for (int r = 1; r < 8; ++r) {
                p0 = pk_fma(rp[r], wp0[r], p0);
                p1 = pk_fma(rp[r], wp1[r], p1);
            }
            const float acc0 = p0[0] + p0[1];   // already scaled: -log2e * z
            const float acc1 = p1[0] + p1[1];

            // --- activations (exp2 consumes pre-scaled inputs directly) ---
            const float a0 = RCPF(EXP2F(acc0) + 1.0f);   // sigma(i) or sigma(f)
            const float s1 = RCPF(EXP2F(acc1) + 1.0f);   // sigma(2g) or sigma(o)
            const float a1 = fmaf(s1, k2, k3);           // SC*tanh(g) or sigma(o)

            // o-broadcast: off the critical path
            const float a1x = partner32(a1, psel_lo);
            const float o_  = halfb ? a1 : a1x;
            const float o2  = o_ + o_;

            // --- C' = sigma(f)*C + sigma(i)*(SC*tanh g) via bit5 exchange ---
            const float m  = a0 * (halfb ? C : a1);
            const float mx = partner32(m, psel_lo);
            C = m + mx;                                  // = SC * c'

            // --- h = o * tanh(c') = fma(sig_c, 2o, -o) ---
            const float sig_c = RCPF(EXP2F(C) + 1.0f);   // sigma(2c')
            h = fmaf(sig_c, o2, -o_);
        }
        xq = xnext;
    }

    // --- epilogue: out[b, :] = h @ w_out.T + b_out ---
    __shared__ float hb[4][H_DIM];
    if (lane < H_DIM) hb[wv][j] = h;    // half0/copy0 lanes; h identical in all
    __syncthreads();

    if (lane < O_DIM) {
        float sacc = b_out[lane];
        #pragma unroll
        for (int k = 0; k < H_DIM; ++k)
            sacc = fmaf(hb[wv][k], w_out[lane * H_DIM + k], sacc);
        out[(size_t)b * O_DIM + lane] = sacc;
    }
}

extern "C" void kernel_launch(void* const* d_in, const int* in_sizes, int n_in,
                              void* d_out, int out_size, void* d_ws, size_t ws_size,
                              hipStream_t stream) {
    const float* x     = (const float*)d_in[0];
    const float* w_ih  = (const float*)d_in[1];
    const float* w_hh  = (const float*)d_in[2];
    const float* b_ih  = (const float*)d_in[3];
    const float* b_hh  = (const float*)d_in[4];
    const float* w_out = (const float*)d_in[5];
    const float* b_out = (const float*)d_in[6];
    float* out = (float*)d_out;

    const int B = in_sizes[0] / T_DIM;          // 2048
    dim3 grid(B / 4), block(256);               // 512 blocks -> 8 waves/CU = 2/SIMD
    hipLaunchKernelGGL(lstm_fused, grid, block, 0, stream,
                       x, w_ih, w_hh, b_ih, b_hh, w_out, b_out, out);
}

// Round 7
// 485.086 us; speedup vs baseline: 1.3727x; 1.3727x over previous
//
#include <hip/hip_runtime.h>

// LSTM: B=2048, T=2048, I=1, H=16, O=26.
//
// Round-7: R6 proved the kernel is VALU-THROUGHPUT-bound (R3 78% busy;
// duplicating work doubled busy cycles and wall time scaled with it), so
// the lever is VALU-busy per batch-step, not occupancy.
//
// Layout: lane = q*16 + j ; q = batch-in-wave (0..3), j = h-index (0..15).
// Each lane owns ALL FOUR gate rows {j, 16+j, 32+j, 48+j} of its batch:
//   - cell update is pure per-lane math (2 FMA) — zero cross-lane ops
//     besides the 15 DPP row_ror rotations, which act on all four 16-lane
//     rows simultaneously (amortized over 4 batches).
//   - per wave-step: 15 DPP + 32 pk_fma + 4 hadd + 4 xb + 10 trans + ~8
//     misc ~= 85 inst for 4 batches (~21/batch vs R3's ~30).
// Math identical to certified R3: weights pre-scaled (i,f,o rows x -log2e;
// g row x -2log2e), cell kept scaled C = -2log2e*c, tanh via sigmoid.
// 512 waves (B/4): half the SIMDs idle — irrelevant when throughput-bound;
// wall = per-wave busy. block=64, grid=512 -> 2 single-wave blocks per CU.

static constexpr int T_DIM = 2048;
static constexpr int H_DIM = 16;
static constexpr int O_DIM = 26;

typedef __attribute__((ext_vector_type(2))) float f32x2;

#define EXP2F(v) __builtin_amdgcn_exp2f(v)
#define RCPF(v)  __builtin_amdgcn_rcpf(v)

// DPP row rotate within 16-lane rows; 0x120|r = row_ror:r (r>=1).
#define ROR_I(x, r) __builtin_amdgcn_update_dpp((x), (x), 0x120 + (r), 0xF, 0xF, false)
#define ROR_F(x, r) __builtin_bit_cast(float, ROR_I(__builtin_bit_cast(int, (x)), (r)))

// Packed dual-FP32 FMA (VOP3P).
__device__ __forceinline__ f32x2 pk_fma(f32x2 a, f32x2 b, f32x2 c) {
    f32x2 d;
    asm("v_pk_fma_f32 %0, %1, %2, %3" : "=v"(d) : "v"(a), "v"(b), "v"(c));
    return d;
}

__global__ __launch_bounds__(64, 1) void lstm_fused(
    const float* __restrict__ x,      // [B, T]
    const float* __restrict__ w_ih,   // [64]
    const float* __restrict__ w_hh,   // [64, 16]
    const float* __restrict__ b_ih,   // [64]
    const float* __restrict__ b_hh,   // [64]
    const float* __restrict__ w_out,  // [26, 16]
    const float* __restrict__ b_out,  // [26]
    float* __restrict__ out)          // [B, 26]
{
    const int lane = threadIdx.x & 63;
    const int j    = lane & 15;
    const int q    = lane >> 4;               // batch within wave
    const int b    = (blockIdx.x << 2) + q;

    // --- DPP direction probes (init-only): idx[r] = source j delivered here.
    int idx[16];
    idx[0]  = j;
    idx[1]  = ROR_I(j, 1);   idx[2]  = ROR_I(j, 2);
    idx[3]  = ROR_I(j, 3);   idx[4]  = ROR_I(j, 4);
    idx[5]  = ROR_I(j, 5);   idx[6]  = ROR_I(j, 6);
    idx[7]  = ROR_I(j, 7);   idx[8]  = ROR_I(j, 8);
    idx[9]  = ROR_I(j, 9);   idx[10] = ROR_I(j, 10);
    idx[11] = ROR_I(j, 11);  idx[12] = ROR_I(j, 12);
    idx[13] = ROR_I(j, 13);  idx[14] = ROR_I(j, 14);
    idx[15] = ROR_I(j, 15);

    // --- scale folding (certified R3 math): i,f,o rows x -log2e; g x -2log2e.
    const float L2E = 1.44269504088896340736f;
    const float SC  = -2.0f * L2E;            // g-row / cell scale
    const float NI  = -L2E;

    const int ri = j, rf = 16 + j, rg = 32 + j, ro = 48 + j;

    // Pre-permuted, pre-scaled weight rows as (k, k+8) pk pairs, one per gate.
    f32x2 wi[8], wf[8], wg[8], wo[8];
    #pragma unroll
    for (int r = 0; r < 8; ++r) {
        wi[r] = (f32x2){w_hh[ri * H_DIM + idx[r]] * NI, w_hh[ri * H_DIM + idx[r + 8]] * NI};
        wf[r] = (f32x2){w_hh[rf * H_DIM + idx[r]] * NI, w_hh[rf * H_DIM + idx[r + 8]] * NI};
        wg[r] = (f32x2){w_hh[rg * H_DIM + idx[r]] * SC, w_hh[rg * H_DIM + idx[r + 8]] * SC};
        wo[r] = (f32x2){w_hh[ro * H_DIM + idx[r]] * NI, w_hh[ro * H_DIM + idx[r + 8]] * NI};
    }
    const float wihi = w_ih[ri] * NI, wihf = w_ih[rf] * NI;
    const float wihg = w_ih[rg] * SC, wiho = w_ih[ro] * NI;
    const float bi = (b_ih[ri] + b_hh[ri]) * NI;
    const float bf = (b_ih[rf] + b_hh[rf]) * NI;
    const float bg = (b_ih[rg] + b_hh[rg]) * SC;
    const float bo = (b_ih[ro] + b_hh[ro]) * NI;

    float C = 0.0f;   // scaled cell state: C = SC * c
    float h = 0.0f;   // h_j of batch q, one value per lane

    const float4* xp = reinterpret_cast<const float4*>(x + (size_t)b * T_DIM);
    float4 xq = xp[0];

    for (int t4 = 0; t4 < T_DIM / 4; ++t4) {
        float4 xnext = xp[(t4 + 1) & (T_DIM / 4 - 1)];  // wraps harmlessly
        const float xa[4] = {xq.x, xq.y, xq.z, xq.w};

        #pragma unroll
        for (int s = 0; s < 4; ++s) {
            // --- 16 alignments of h as 8 pk pairs (15 independent DPPs);
            //     row_ror acts within each 16-lane row = within each batch.
            f32x2 rp[8];
            rp[0][0] = h;            rp[0][1] = ROR_F(h, 8);
            rp[1][0] = ROR_F(h, 1);  rp[1][1] = ROR_F(h, 9);
            rp[2][0] = ROR_F(h, 2);  rp[2][1] = ROR_F(h, 10);
            rp[3][0] = ROR_F(h, 3);  rp[3][1] = ROR_F(h, 11);
            rp[4][0] = ROR_F(h, 4);  rp[4][1] = ROR_F(h, 12);
            rp[5][0] = ROR_F(h, 5);  rp[5][1] = ROR_F(h, 13);
            rp[6][0] = ROR_F(h, 6);  rp[6][1] = ROR_F(h, 14);
            rp[7][0] = ROR_F(h, 7);  rp[7][1] = ROR_F(h, 15);

            // --- 4 gate dots: 4 independent chains of 8 pk_fma ---
            f32x2 pi = pk_fma(rp[0], wi[0], (f32x2){fmaf(xa[s], wihi, bi), 0.0f});
            f32x2 pf = pk_fma(rp[0], wf[0], (f32x2){fmaf(xa[s], wihf, bf), 0.0f});
            f32x2 pg = pk_fma(rp[0], wg[0], (f32x2){fmaf(xa[s], wihg, bg), 0.0f});
            f32x2 po = pk_fma(rp[0], wo[0], (f32x2){fmaf(xa[s], wiho, bo), 0.0f});
            #pragma unroll
            for (int r = 1; r < 8; ++r) {
                pi = pk_fma(rp[r], wi[r], pi);
                pf = pk_fma(rp[r], wf[r], pf);
                pg = pk_fma(rp[r], wg[r], pg);
                po = pk_fma(rp[r], wo[r], po);
            }
            const float zi = pi[0] + pi[1];   // pre-scaled gate pre-acts
            const float zf = pf[0] + pf[1];
            const float zg = pg[0] + pg[1];
            const float zo = po[0] + po[1];

            // --- activations: sigma(z) = 1/(1 + 2^(-log2e*z)) ---
            const float ai = RCPF(EXP2F(zi) + 1.0f);
            const float af = RCPF(EXP2F(zf) + 1.0f);
            const float sg = RCPF(EXP2F(zg) + 1.0f);  // sigma(2g)
            const float ao = RCPF(EXP2F(zo) + 1.0f);

            // --- cell + hidden, pure per-lane ---
            const float tg = fmaf(sg, 2.0f * SC, -SC);  // SC * tanh(g)
            C = fmaf(af, C, ai * tg);                   // = SC * c'
            const float sig_c = RCPF(EXP2F(C) + 1.0f);  // sigma(2c')
            h = fmaf(sig_c, ao + ao, -ao);              // o * tanh(c')
        }
        xq = xnext;
    }

    // --- epilogue: out[b_base+q, :] = h(q,:) @ w_out.T + b_out ---
    __shared__ float hb[4][H_DIM];
    hb[q][j] = h;                          // 64 lanes, 64 distinct slots
    __builtin_amdgcn_wave_barrier();

    #pragma unroll
    for (int p = 0; p < 2; ++p) {
        const int oidx = p * 64 + lane;    // 0..103 = 4 batches x 26 outputs
        if (oidx < 4 * O_DIM) {
            const int qq = oidx / O_DIM;
            const int oi = oidx - qq * O_DIM;
            float sacc = b_out[oi];
            #pragma unroll
            for (int k = 0; k < H_DIM; ++k)
                sacc = fmaf(hb[qq][k], w_out[oi * H_DIM + k], sacc);
            out[(size_t)((blockIdx.x << 2) + qq) * O_DIM + oi] = sacc;
        }
    }
}

extern "C" void kernel_launch(void* const* d_in, const int* in_sizes, int n_in,
                              void* d_out, int out_size, void* d_ws, size_t ws_size,
                              hipStream_t stream) {
    const float* x     = (const float*)d_in[0];
    const float* w_ih  = (const float*)d_in[1];
    const float* w_hh  = (const float*)d_in[2];
    const float* b_ih  = (const float*)d_in[3];
    const float* b_hh  = (const float*)d_in[4];
    const float* w_out = (const float*)d_in[5];
    const float* b_out = (const float*)d_in[6];
    float* out = (float*)d_out;

    const int B = in_sizes[0] / T_DIM;          // 2048
    dim3 grid(B / 4), block(64);                // 512 single-wave blocks
    hipLaunchKernelGGL(lstm_fused, grid, block, 0, stream,
                       x, w_ih, w_hh, b_ih, b_hh, w_out, b_out, out);
}